// Round 5
// baseline (222.004 us; speedup 1.0000x reference)
//
#include <hip/hip_runtime.h>

// Causal GQA flash attention fwd, MI355X (gfx950).
// B=2 HQ=32 HKV=8 S=2048 D=128, fp32 in/out, bf16 MFMA compute.
// Structure (HK/AITER ts_qo=256, ts_kv=64 shape): 512 thr / 8 waves,
// 32 q-rows per wave, 32x32x16 MFMA with swapped QK^T (S^T = K*Q^T) so
// softmax is lane-local; cross-half exchange via __shfl_xor(.,32) ONLY
// (defined semantics; permlane32_swap removed after r3 validation fail).
// P stays in registers (T12-style repack); K + V^T double-buffered in
// XOR-swizzled LDS, reg-staged (T14), ONE barrier per KV tile, T13
// defer-max (THR=8). Each block: PAIR of q-tiles (qt, 7-qt) -> constant
// 36 KV-tiles/block, 256 blocks = 1/CU, bijective XCD swizzle.

#define SEQ   2048
#define DH    128
#define NBATCH 2
#define NHQ   32
#define NHKV  8
#define QT    256
#define KT    64

typedef __bf16 bf16_t;
typedef bf16_t bf16x8 __attribute__((ext_vector_type(8)));
typedef bf16_t bf16x4 __attribute__((ext_vector_type(4)));
typedef bf16_t bf16x2 __attribute__((ext_vector_type(2)));
typedef short  short8 __attribute__((ext_vector_type(8)));
typedef float  f32x4  __attribute__((ext_vector_type(4)));
typedef float  f32x16 __attribute__((ext_vector_type(16)));
typedef unsigned int u32;
typedef u32    u32x4  __attribute__((ext_vector_type(4)));

__device__ __forceinline__ f32x16 mfma32(bf16x8 a, bf16x8 b, f32x16 c) {
  return __builtin_amdgcn_mfma_f32_32x32x16_bf16(
      __builtin_bit_cast(short8, a), __builtin_bit_cast(short8, b), c, 0, 0, 0);
}
__device__ __forceinline__ float fexp2(float x) {
  float r; asm("v_exp_f32 %0, %1" : "=v"(r) : "v"(x)); return r;
}
// pack two f32 -> one u32 of 2 bf16 via plain casts (compiler emits cvt_pk)
__device__ __forceinline__ u32 pack2(float lo, float hi) {
  bf16x2 t; t[0] = (bf16_t)lo; t[1] = (bf16_t)hi;
  return __builtin_bit_cast(u32, t);
}

__launch_bounds__(512, 2)
__global__ void fa_fwd(const float* __restrict__ Q, const float* __restrict__ K,
                       const float* __restrict__ V, float* __restrict__ O) {
  // softmax scale folded into Q together with log2(e) -> exp via v_exp_f32
  constexpr float QSCALE = 0.08838834764831845f * 1.44269504088896340736f;

  const int tid  = threadIdx.x;
  const int lane = tid & 63;
  const int w    = tid >> 6;          // wave 0..7
  const int l31  = lane & 31;
  const int h    = lane >> 5;         // half-wave 0/1
  const int h4   = h << 2, h8 = h << 3;

  // bijective XCD swizzle: XCD x (= draw%8) hosts 32 consecutive logical bids
  const int draw = blockIdx.x;
  const int bid  = (draw & 7) * 32 + (draw >> 3);
  const int p    = bid & 3;           // q-tile pair id
  const int hq   = (bid >> 2) & 31;
  const int b    = bid >> 7;
  const int hkv  = hq >> 2;           // GQA group of 4

  __shared__ __align__(16) bf16_t Kl[2][KT * DH];  // K tile row-major, swizzled
  __shared__ __align__(16) bf16_t Vt[2][DH * KT];  // V^T tile [d][kv], swizzled

  const float* Qg = Q + ((size_t)(b * NHQ + hq)) * SEQ * DH;
  const float* Kg = K + ((size_t)(b * NHKV + hkv)) * SEQ * DH;
  const float* Vg = V + ((size_t)(b * NHKV + hkv)) * SEQ * DH;
  float*       Og = O + ((size_t)(b * NHQ + hq)) * SEQ * DH;

  // staging registers (prefetch tile t+1 while computing t)
  f32x4 kreg[4], vreg[4];
  const int kvp = (tid & 31) << 1;    // V: pair of source rows (kv, kv+1)
  const int dgp = (tid >> 5) << 3;    // V: 8-float d-group base

  auto issue_loads = [&](int t) {
    const float* kg = Kg + ((size_t)t << 6) * DH;
    #pragma unroll
    for (int i = 0; i < 4; ++i) {
      int c = tid + (i << 9);
      kreg[i] = *(const f32x4*)(kg + (c >> 5) * DH + ((c & 31) << 2));
    }
    const float* vp = Vg + ((size_t)((t << 6) + kvp)) * DH + dgp;
    vreg[0] = *(const f32x4*)(vp);
    vreg[1] = *(const f32x4*)(vp + 4);
    vreg[2] = *(const f32x4*)(vp + DH);
    vreg[3] = *(const f32x4*)(vp + DH + 4);
  };
  auto write_tile = [&](int bf) {
    #pragma unroll
    for (int i = 0; i < 4; ++i) {
      int c = tid + (i << 9);
      int row = c >> 5, col = (c & 31) << 2;
      f32x4 f = kreg[i];
      bf16x4 hh;
      hh[0] = (bf16_t)f[0]; hh[1] = (bf16_t)f[1];
      hh[2] = (bf16_t)f[2]; hh[3] = (bf16_t)f[3];
      *(bf16x4*)(&Kl[bf][(row * DH + col) ^ ((row & 7) << 3)]) = hh;
    }
    // V^T: one b32 write = {V[kv][d], V[kv+1][d]} (paired rows, conflict-free)
    #pragma unroll
    for (int j = 0; j < 8; ++j) {
      int d = dgp + j;
      bf16x2 pk;
      pk[0] = (bf16_t)vreg[j >> 2][j & 3];
      pk[1] = (bf16_t)vreg[2 + (j >> 2)][j & 3];
      *(bf16x2*)(&Vt[bf][(d * KT + kvp) ^ ((d & 7) << 3)]) = pk;
    }
  };

  // ---- two q-tiles per block: qt = 7-p then p (constant total work)
  #pragma unroll 1
  for (int qi = 0; qi < 2; ++qi) {
    const int qt  = qi ? p : (7 - p);
    const int q0  = qt * QT;
    const int q0w = q0 + w * 32;      // this wave's first q row
    const int qg  = q0w + l31;        // this lane's q row (owns its softmax)

    // ---- Q B-frags: B[k=d][col=q], col=lane&31, k-elems d = ds*16+h8+(0..7)
    bf16x8 qf[8];
    {
      const float* qp = Qg + (size_t)qg * DH;
      #pragma unroll
      for (int ds = 0; ds < 8; ++ds) {
        f32x4 a = *(const f32x4*)(qp + ds * 16 + h8);
        f32x4 c = *(const f32x4*)(qp + ds * 16 + h8 + 4);
        bf16x8 tq;
        tq[0] = (bf16_t)(a[0] * QSCALE); tq[1] = (bf16_t)(a[1] * QSCALE);
        tq[2] = (bf16_t)(a[2] * QSCALE); tq[3] = (bf16_t)(a[3] * QSCALE);
        tq[4] = (bf16_t)(c[0] * QSCALE); tq[5] = (bf16_t)(c[1] * QSCALE);
        tq[6] = (bf16_t)(c[2] * QSCALE); tq[7] = (bf16_t)(c[3] * QSCALE);
        qf[ds] = tq;
      }
    }

    f32x16 acc[4];                    // O^T accum: row=d_local, col=q
    #pragma unroll
    for (int d = 0; d < 4; ++d)
      #pragma unroll
      for (int j = 0; j < 16; ++j) acc[d][j] = 0.f;
    float mrun = -1e30f, lrun = 0.f;

    issue_loads(0);
    __syncthreads();                  // previous q-tile's LDS readers done
    write_tile(0);
    __syncthreads();

    const int lastT = (q0 >> 6) + 3;
    for (int t = 0; t <= lastT; ++t) {
      const int cur = t & 1;
      const int kv0 = t << 6;
      const bool pf = (t < lastT);
      if (pf) issue_loads(t + 1);     // in flight across compute (T14)

      if (kv0 < q0w + 32) {           // wave has unmasked rows in this tile
        // ---- S^T = K * Q^T : A=K (row=kv_local), B=Q (col=q)
        f32x16 sc[2];
        #pragma unroll
        for (int nb = 0; nb < 2; ++nb)
          #pragma unroll
          for (int j = 0; j < 16; ++j) sc[nb][j] = 0.f;

        __builtin_amdgcn_s_setprio(1);
        #pragma unroll
        for (int nb = 0; nb < 2; ++nb) {
          #pragma unroll
          for (int ds = 0; ds < 8; ++ds) {
            int row = nb * 32 + l31;
            bf16x8 kf = *(const bf16x8*)(
                &Kl[cur][(row * DH + ds * 16 + h8) ^ ((row & 7) << 3)]);
            sc[nb] = mfma32(kf, qf[ds], sc[nb]);
          }
        }
        __builtin_amdgcn_s_setprio(0);

        // ---- causal mask (diagonal tiles only); C row = (r&3)+8(r>>2)+4h
        if (kv0 + KT - 1 > q0w) {
          #pragma unroll
          for (int nb = 0; nb < 2; ++nb)
            #pragma unroll
            for (int r = 0; r < 16; ++r) {
              int kvg = kv0 + nb * 32 + (r & 3) + ((r >> 2) << 3) + h4;
              if (kvg > qg) sc[nb][r] = -1e30f;
            }
        }

        // ---- online softmax: 4-acc local tree, combine halves via shfl_xor(32)
        float mx0 = fmaxf(sc[0][0], sc[1][0]);
        float mx1 = fmaxf(sc[0][1], sc[1][1]);
        float mx2 = fmaxf(sc[0][2], sc[1][2]);
        float mx3 = fmaxf(sc[0][3], sc[1][3]);
        #pragma unroll
        for (int j = 4; j < 16; j += 4) {
          mx0 = fmaxf(mx0, fmaxf(sc[0][j + 0], sc[1][j + 0]));
          mx1 = fmaxf(mx1, fmaxf(sc[0][j + 1], sc[1][j + 1]));
          mx2 = fmaxf(mx2, fmaxf(sc[0][j + 2], sc[1][j + 2]));
          mx3 = fmaxf(mx3, fmaxf(sc[0][j + 3], sc[1][j + 3]));
        }
        float vloc = fmaxf(fmaxf(mx0, mx1), fmaxf(mx2, mx3));
        float vmax = fmaxf(vloc, __shfl_xor(vloc, 32));  // both halves of q row

        // ---- T13 defer-max: rescale only when max grew by > 8 (log2 domain)
        if (!__all(vmax - mrun <= 8.0f)) {
          float mn = fmaxf(mrun, vmax);
          float al = fexp2(mrun - mn);
          mrun = mn;
          lrun *= al;
          #pragma unroll
          for (int d = 0; d < 4; ++d)
            #pragma unroll
            for (int j = 0; j < 16; ++j) acc[d][j] *= al;
        }

        float s0 = 0.f, s1 = 0.f, s2 = 0.f, s3 = 0.f;
        #pragma unroll
        for (int nb = 0; nb < 2; ++nb)
          #pragma unroll
          for (int j = 0; j < 16; j += 4) {
            sc[nb][j + 0] = fexp2(sc[nb][j + 0] - mrun); s0 += sc[nb][j + 0];
            sc[nb][j + 1] = fexp2(sc[nb][j + 1] - mrun); s1 += sc[nb][j + 1];
            sc[nb][j + 2] = fexp2(sc[nb][j + 2] - mrun); s2 += sc[nb][j + 2];
            sc[nb][j + 3] = fexp2(sc[nb][j + 3] - mrun); s3 += sc[nb][j + 3];
          }
        float ssum = (s0 + s1) + (s2 + s3);
        lrun += ssum + __shfl_xor(ssum, 32);

        // ---- P (C-layout) -> PV B-frags, shfl_xor(32)-based repack.
        // pfrag[nb*2+ks] elem i on lane (l31,h) = P[nb*32+ks*16+h*8+i][l31]
        //   = sc[nb][r], r=(i&3)+8*ks+4*h, from half hsrc=(i>>2).
        bf16x8 pfrag[4];
        #pragma unroll
        for (int nb = 0; nb < 2; ++nb) {
          #pragma unroll
          for (int ks = 0; ks < 2; ++ks) {
            u32 c01 = pack2(sc[nb][8 * ks + 0], sc[nb][8 * ks + 1]);
            u32 c23 = pack2(sc[nb][8 * ks + 2], sc[nb][8 * ks + 3]);
            u32 c45 = pack2(sc[nb][8 * ks + 4], sc[nb][8 * ks + 5]);
            u32 c67 = pack2(sc[nb][8 * ks + 6], sc[nb][8 * ks + 7]);
            // send the half the partner needs: h=0 sends r=8ks+4..7, h=1 sends 8ks+0..3
            u32 s01 = h ? c01 : c45;
            u32 s23 = h ? c23 : c67;
            u32 r01 = __shfl_xor(s01, 32);
            u32 r23 = __shfl_xor(s23, 32);
            u32x4 uf;
            uf[0] = h ? r01 : c01;    // elems 0,1  (hsrc=0, r=8ks+4h+0,1)
            uf[1] = h ? r23 : c23;    // elems 2,3
            uf[2] = h ? c45 : r01;    // elems 4,5  (hsrc=1, r=8ks+4h+0,1)
            uf[3] = h ? c67 : r23;    // elems 6,7
            pfrag[nb * 2 + ks] = __builtin_bit_cast(bf16x8, uf);
          }
        }

        // ---- O^T += V^T * P^T : A=V^T (row=d_local), B=P^T (col=q)
        __builtin_amdgcn_s_setprio(1);
        #pragma unroll
        for (int db = 0; db < 4; ++db) {
          #pragma unroll
          for (int ks = 0; ks < 4; ++ks) {
            int row = db * 32 + l31;
            bf16x8 vf = *(const bf16x8*)(
                &Vt[cur][(row * KT + ks * 16 + h8) ^ ((row & 7) << 3)]);
            acc[db] = mfma32(vf, pfrag[ks], acc[db]);
          }
        }
        __builtin_amdgcn_s_setprio(0);
      }

      if (pf) {
        write_tile(cur ^ 1);          // buf[cur^1]'s readers crossed barrier(t-1)
        __syncthreads();              // writes visible before tile t+1 reads
      }
    }

    // ---- epilogue: O[q][d] = acc/l ; d = db*32 + 8s + 4h + r
    float inv = 1.0f / lrun;
    float* op = Og + (size_t)qg * DH;
    #pragma unroll
    for (int db = 0; db < 4; ++db)
      #pragma unroll
      for (int s = 0; s < 4; ++s) {
        f32x4 st;
        st[0] = acc[db][4 * s + 0] * inv;
        st[1] = acc[db][4 * s + 1] * inv;
        st[2] = acc[db][4 * s + 2] * inv;
        st[3] = acc[db][4 * s + 3] * inv;
        *(f32x4*)(op + db * 32 + s * 8 + h4) = st;
      }
  }
}

extern "C" void kernel_launch(void* const* d_in, const int* in_sizes, int n_in,
                              void* d_out, int out_size, void* d_ws, size_t ws_size,
                              hipStream_t stream) {
  const float* q = (const float*)d_in[0];
  const float* k = (const float*)d_in[1];
  const float* v = (const float*)d_in[2];
  float* out = (float*)d_out;
  (void)in_sizes; (void)n_in; (void)out_size; (void)d_ws; (void)ws_size;

  dim3 grid(NBATCH * NHQ * (SEQ / QT / 2));  // 2*32*4 = 256 blocks (q-tile pairs)
  dim3 block(512);
  fa_fwd<<<grid, block, 0, stream>>>(q, k, v, out);
}